// Round 5
// baseline (519.157 us; speedup 1.0000x reference)
//
#include <hip/hip_runtime.h>
#include <hip/hip_bf16.h>

#define N_TOK 2048
#define B_SZ  8
#define E_DIM 256
#define H_DIM 512
#define ITERS (N_TOK / 32)     // 64

typedef __attribute__((ext_vector_type(8))) short bf16x8;
typedef __attribute__((ext_vector_type(4))) float f32x4;

__device__ __forceinline__ unsigned short f2bf(float f) {
    union { float f; unsigned u; } v; v.f = f;
    unsigned r = v.u + 0x7FFF + ((v.u >> 16) & 1);   // RNE
    return (unsigned short)(r >> 16);
}
__device__ __forceinline__ float bf2f(unsigned short b) {
    union { unsigned u; float f; } v; v.u = ((unsigned)b) << 16;
    return v.f;
}

// ---- Kernel 1: row-normalize x -> Xn bf16 (B,N,E), 16B units XOR-swizzled --
// unit u of row r stored at position u ^ (r & 7)  (u = e/8, 32 units/row)
__global__ void norm_kernel(const float* __restrict__ x,
                            unsigned short* __restrict__ Xn) {
    int r = blockIdx.x;            // r = i*B + b  (memory order of x)
    int i = r >> 3, b = r & 7;
    int t = threadIdx.x;           // 256 threads == E_DIM
    float v = x[(size_t)r * E_DIM + t];
    float s = v * v;
    #pragma unroll
    for (int o = 32; o > 0; o >>= 1) s += __shfl_xor(s, o);
    __shared__ float red[4];
    int lane = t & 63, w = t >> 6;
    if (lane == 0) red[w] = s;
    __syncthreads();
    float tot = red[0] + red[1] + red[2] + red[3];
    float rn = 1.0f / sqrtf(tot);
    int u = t >> 3, lo = t & 7;
    Xn[((size_t)b * N_TOK + i) * E_DIM + (size_t)((u ^ (i & 7)) * 8 + lo)] =
        f2bf(v * rn);
}

// ---- Kernel 2: pack h (N,B,H) f32 -> Vp (B, N/32, H, 32) bf16, swizzled ----
// Within a 32-key tile: 16B unit (h, jg) (jg=j'/8) stored at h*4 + (jg ^ ((h>>1)&3)).
__global__ void pack_v(const float* __restrict__ h,
                       unsigned short* __restrict__ Vp) {
    __shared__ float tile[32][33];
    int j0 = blockIdx.x * 32, h0 = blockIdx.y * 32, b = blockIdx.z;
    int tx = threadIdx.x & 31, ty = threadIdx.x >> 5;   // 32 x 8
    #pragma unroll
    for (int it = 0; it < 4; it++) {
        int j = j0 + ty + it * 8;
        tile[ty + it * 8][tx] = h[((size_t)j * B_SZ + b) * H_DIM + h0 + tx];
    }
    __syncthreads();
    size_t base = ((size_t)b * (N_TOK / 32) + blockIdx.x) * (H_DIM * 32);
    #pragma unroll
    for (int it = 0; it < 4; it++) {
        int hc = h0 + ty + it * 8;           // h column
        int jg = tx >> 3, swz = (hc >> 1) & 3;
        Vp[base + (size_t)(hc * 4 + (jg ^ swz)) * 8 + (tx & 7)] =
            f2bf(tile[tx][ty + it * 8]);
    }
}

// ---- Kernel 3: fused flash attention, split-h -----------------------------
// grid (B=8, N/32=64, 2): x=batch (XCD pin: linear id % 8 == batch),
// y=q-tile, z=h-half. 256 threads (4 waves). Wave w: rg=w>>1 (16 q-rows,
// QK dup x2), hh2=w&1 (128 h-cols within the block's 256-h half).
// Target 4 blocks/CU (LDS 37.9KB x4 <= 160KB, VGPR capped at 128).
#define PT_STRIDE 40   // shorts

__launch_bounds__(256, 4)
__global__ void flash_kernel(const unsigned short* __restrict__ Xn,
                             const unsigned short* __restrict__ Vp,
                             float* __restrict__ out,
                             float* __restrict__ sumsq) {
    __shared__ __attribute__((aligned(16))) unsigned short Kbuf[2][32 * 256];
    __shared__ __attribute__((aligned(16))) unsigned short Pt[4][16 * PT_STRIDE];

    int b  = blockIdx.x;           // batch: linear-id % 8 == b -> XCD-pinned
    int q0 = blockIdx.y * 32;
    int zh = blockIdx.z;
    int t = threadIdx.x;
    int w = t >> 6, lane = t & 63;
    int quad = lane >> 4, nm = lane & 15;
    int rg = w >> 1, hh2 = w & 1;
    int hbase = zh * 256 + hh2 * 128;

    const unsigned short* Kbase = Xn + (size_t)b * N_TOK * E_DIM;
    const unsigned short* Qrow =
        Xn + ((size_t)b * N_TOK + q0 + rg * 16 + nm) * E_DIM;
    const unsigned short* Vtile0 = Vp + (size_t)b * (N_TOK / 32) * (H_DIM * 32);

    // Q fragments (swizzled layout: unit (ec*4+quad) ^ (row&7))
    bf16x8 qf[8];
    #pragma unroll
    for (int ec = 0; ec < 8; ec++)
        qf[ec] = *(const bf16x8*)(Qrow + (size_t)(((ec * 4 + quad) ^ (nm & 7)) * 8));

    f32x4 O[8];
    #pragma unroll
    for (int i = 0; i < 8; i++) O[i] = (f32x4){0.f, 0.f, 0.f, 0.f};
    float m_cur[4], l_cur[4];
    #pragma unroll
    for (int r = 0; r < 4; r++) { m_cur[r] = -INFINITY; l_cur[r] = 0.0f; }

    // K staging: straight sequential copy of the 16KB tile (swizzle pre-baked)
    auto stage = [&](int tile, int buf) {
        const unsigned short* src0 = Kbase + (size_t)tile * 32 * E_DIM;
        #pragma unroll
        for (int k = 0; k < 4; k++) {
            int chunk = w * 4 + k;                 // 0..15, 1KB each
            __builtin_amdgcn_global_load_lds(
                (const __attribute__((address_space(1))) unsigned int*)
                    (src0 + (size_t)chunk * 512 + lane * 8),
                (__attribute__((address_space(3))) unsigned int*)
                    (&Kbuf[buf][chunk * 512]),
                16, 0, 0);
        }
    };

    stage(0, 0);
    int vswz = (quad ^ ((nm >> 1) & 3)) * 8;

    for (int it = 0; it < ITERS; ++it) {
        __syncthreads();                 // drains staging of tile `it`
        int cur = it & 1;

        // ---- V fragment prefetch (this iter), contiguous 1KB per instr ----
        const unsigned short* Vt = Vtile0 + (size_t)it * (H_DIM * 32);
        bf16x8 vf[8];
        #pragma unroll
        for (int tt = 0; tt < 8; tt++) {
            int hc = hbase + tt * 16 + nm;
            vf[tt] = *(const bf16x8*)(Vt + (size_t)(hc * 4) * 8 + vswz);
        }

        if (it + 1 < ITERS) stage(it + 1, cur ^ 1);
        const unsigned short* KB = &Kbuf[cur][0];

        // ---- QK^T: 16 q-rows x 32 keys, K=256 ----
        f32x4 s0 = (f32x4){0.f,0.f,0.f,0.f}, s1 = (f32x4){0.f,0.f,0.f,0.f};
        #pragma unroll
        for (int ec = 0; ec < 8; ec++) {
            int u = ((ec * 4 + quad) ^ (nm & 7)) * 8;
            bf16x8 kf0 = *(const bf16x8*)(KB + nm * 256 + u);
            bf16x8 kf1 = *(const bf16x8*)(KB + (16 + nm) * 256 + u);
            s0 = __builtin_amdgcn_mfma_f32_16x16x32_bf16(qf[ec], kf0, s0, 0, 0, 0);
            s1 = __builtin_amdgcn_mfma_f32_16x16x32_bf16(qf[ec], kf1, s1, 0, 0, 0);
        }

        // ---- wave-local online softmax (rows quad*4+r, reduce over 16 nm) --
        float alpha[4];
        #pragma unroll
        for (int r = 0; r < 4; r++) {
            float v = fmaxf(s0[r], s1[r]);
            #pragma unroll
            for (int o = 1; o < 16; o <<= 1) v = fmaxf(v, __shfl_xor(v, o));
            float mn = fmaxf(m_cur[r], v);
            alpha[r] = __expf(m_cur[r] - mn);
            m_cur[r] = mn;
            unsigned short pb0 = f2bf(__expf(s0[r] - mn));
            unsigned short pb1 = f2bf(__expf(s1[r] - mn));
            float ps = bf2f(pb0) + bf2f(pb1);
            #pragma unroll
            for (int o = 1; o < 16; o <<= 1) ps += __shfl_xor(ps, o);
            l_cur[r] = l_cur[r] * alpha[r] + ps;
            Pt[w][(quad * 4 + r) * PT_STRIDE + nm]      = pb0;
            Pt[w][(quad * 4 + r) * PT_STRIDE + 16 + nm] = pb1;
        }

        // ---- rescale O while the Pt writes land ----
        #pragma unroll
        for (int tt = 0; tt < 8; tt++)
            #pragma unroll
            for (int r = 0; r < 4; r++)
                O[tt][r] *= alpha[r];

        asm volatile("s_waitcnt lgkmcnt(0)" ::: "memory");
        __builtin_amdgcn_wave_barrier();
        bf16x8 pf = *(const bf16x8*)(&Pt[w][nm * PT_STRIDE + quad * 8]);

        // ---- PV (8 col-tiles x K=32) ----
        #pragma unroll
        for (int tt = 0; tt < 8; tt++)
            O[tt] = __builtin_amdgcn_mfma_f32_16x16x32_bf16(pf, vf[tt], O[tt], 0, 0, 0);
    }

    // ---- epilogue: divide by l, write unnormalized g, accumulate sumsq ----
    float linv[4];
    #pragma unroll
    for (int r = 0; r < 4; r++) linv[r] = 1.0f / l_cur[r];

    float ss = 0.0f;
    #pragma unroll
    for (int tt = 0; tt < 8; tt++) {
        #pragma unroll
        for (int r = 0; r < 4; r++) {
            float val = O[tt][r] * linv[r];
            int row = q0 + rg * 16 + quad * 4 + r;
            int col = hbase + tt * 16 + nm;
            out[((size_t)row * B_SZ + b) * H_DIM + col] = val;
            ss += val * val;
        }
    }
    #pragma unroll
    for (int o = 1; o < 64; o <<= 1) ss += __shfl_xor(ss, o);
    if (lane == 0) atomicAdd(sumsq, ss);
}

// ---- Kernel 4: global-norm rescale ----------------------------------------
__global__ void scale_kernel(float* __restrict__ out,
                             const float* __restrict__ sumsq) {
    size_t idx = ((size_t)blockIdx.x * blockDim.x + threadIdx.x) * 4;
    float rs = 1.0f / sqrtf(*sumsq);
    float4 v = *(float4*)(out + idx);
    v.x *= rs; v.y *= rs; v.z *= rs; v.w *= rs;
    *(float4*)(out + idx) = v;
}

extern "C" void kernel_launch(void* const* d_in, const int* in_sizes, int n_in,
                              void* d_out, int out_size, void* d_ws, size_t ws_size,
                              hipStream_t stream) {
    const float* x = (const float*)d_in[0];
    const float* h = (const float*)d_in[1];
    float* out = (float*)d_out;

    unsigned short* Xn = (unsigned short*)d_ws;                  // 8.4 MB
    unsigned short* Vp = Xn + (size_t)B_SZ * N_TOK * E_DIM;      // 16.8 MB
    float* sumsq = (float*)(Vp + (size_t)B_SZ * N_TOK * H_DIM); // 4 B

    hipMemsetAsync(sumsq, 0, sizeof(float), stream);
    norm_kernel<<<N_TOK * B_SZ, 256, 0, stream>>>(x, Xn);
    pack_v<<<dim3(N_TOK / 32, H_DIM / 32, B_SZ), 256, 0, stream>>>(h, Vp);
    flash_kernel<<<dim3(B_SZ, N_TOK / 32, 2), 256, 0, stream>>>(Xn, Vp, out, sumsq);
    scale_kernel<<<out_size / (4 * 256), 256, 0, stream>>>(out, sumsq);
}

// Round 6
// 367.968 us; speedup vs baseline: 1.4109x; 1.4109x over previous
//
#include <hip/hip_runtime.h>
#include <hip/hip_bf16.h>

#define N_TOK 2048
#define B_SZ  8
#define E_DIM 256
#define H_DIM 512
#define ITERS (N_TOK / 32)     // 64

typedef __attribute__((ext_vector_type(8))) short bf16x8;
typedef __attribute__((ext_vector_type(4))) float f32x4;

__device__ __forceinline__ unsigned short f2bf(float f) {
    union { float f; unsigned u; } v; v.f = f;
    unsigned r = v.u + 0x7FFF + ((v.u >> 16) & 1);   // RNE
    return (unsigned short)(r >> 16);
}
__device__ __forceinline__ float bf2f(unsigned short b) {
    union { unsigned u; float f; } v; v.u = ((unsigned)b) << 16;
    return v.f;
}

// ---- Kernel 1: row-normalize x -> Xn bf16 (B,N,E), 16B units XOR-swizzled --
// unit u of row r stored at position u ^ (r & 7)  (u = e/8, 32 units/row)
__global__ void norm_kernel(const float* __restrict__ x,
                            unsigned short* __restrict__ Xn) {
    int r = blockIdx.x;            // r = i*B + b  (memory order of x)
    int i = r >> 3, b = r & 7;
    int t = threadIdx.x;           // 256 threads == E_DIM
    float v = x[(size_t)r * E_DIM + t];
    float s = v * v;
    #pragma unroll
    for (int o = 32; o > 0; o >>= 1) s += __shfl_xor(s, o);
    __shared__ float red[4];
    int lane = t & 63, w = t >> 6;
    if (lane == 0) red[w] = s;
    __syncthreads();
    float tot = red[0] + red[1] + red[2] + red[3];
    float rn = 1.0f / sqrtf(tot);
    int u = t >> 3, lo = t & 7;
    Xn[((size_t)b * N_TOK + i) * E_DIM + (size_t)((u ^ (i & 7)) * 8 + lo)] =
        f2bf(v * rn);
}

// ---- Kernel 2: pack h (N,B,H) f32 -> Vp (B, N/32, H, 32) bf16, swizzled ----
// Within a 32-key tile: 16B unit (h, jg) (jg=j'/8) stored at h*4 + (jg ^ ((h>>1)&3)).
__global__ void pack_v(const float* __restrict__ h,
                       unsigned short* __restrict__ Vp) {
    __shared__ float tile[32][33];
    int j0 = blockIdx.x * 32, h0 = blockIdx.y * 32, b = blockIdx.z;
    int tx = threadIdx.x & 31, ty = threadIdx.x >> 5;   // 32 x 8
    #pragma unroll
    for (int it = 0; it < 4; it++) {
        int j = j0 + ty + it * 8;
        tile[ty + it * 8][tx] = h[((size_t)j * B_SZ + b) * H_DIM + h0 + tx];
    }
    __syncthreads();
    size_t base = ((size_t)b * (N_TOK / 32) + blockIdx.x) * (H_DIM * 32);
    #pragma unroll
    for (int it = 0; it < 4; it++) {
        int hc = h0 + ty + it * 8;           // h column
        int jg = tx >> 3, swz = (hc >> 1) & 3;
        Vp[base + (size_t)(hc * 4 + (jg ^ swz)) * 8 + (tx & 7)] =
            f2bf(tile[tx][ty + it * 8]);
    }
}

// ---- Kernel 3: fused flash attention, split-h -----------------------------
// grid (B=8, N/32=64, 2): x=batch (XCD pin: linear id % 8 == batch),
// y=q-tile, z=h-half. 256 threads (4 waves). Wave w: rg=w>>1 (16 q-rows,
// QK dup x2), hh2=w&1 (128 h-cols within the block's 256-h half).
// launch_bounds(256,3): VGPR budget ~168 so the allocator lands ~112 (no
// spills — R5's (256,4) forced 64 VGPR and scratch-spilled the vf prefetch);
// at <=128 VGPR the HW still allows 4 blocks/CU (LDS 37.9KB x4 <= 160KB).
#define PT_STRIDE 40   // shorts

__launch_bounds__(256, 3)
__global__ void flash_kernel(const unsigned short* __restrict__ Xn,
                             const unsigned short* __restrict__ Vp,
                             float* __restrict__ out,
                             float* __restrict__ sumsq) {
    __shared__ __attribute__((aligned(16))) unsigned short Kbuf[2][32 * 256];
    __shared__ __attribute__((aligned(16))) unsigned short Pt[4][16 * PT_STRIDE];

    int b  = blockIdx.x;           // batch: linear-id % 8 == b -> XCD-pinned
    int q0 = blockIdx.y * 32;
    int zh = blockIdx.z;
    int t = threadIdx.x;
    int w = t >> 6, lane = t & 63;
    int quad = lane >> 4, nm = lane & 15;
    int rg = w >> 1, hh2 = w & 1;
    int hbase = zh * 256 + hh2 * 128;

    const unsigned short* Kbase = Xn + (size_t)b * N_TOK * E_DIM;
    const unsigned short* Qrow =
        Xn + ((size_t)b * N_TOK + q0 + rg * 16 + nm) * E_DIM;
    const unsigned short* Vtile0 = Vp + (size_t)b * (N_TOK / 32) * (H_DIM * 32);

    // Q fragments (swizzled layout: unit (ec*4+quad) ^ (row&7))
    bf16x8 qf[8];
    #pragma unroll
    for (int ec = 0; ec < 8; ec++)
        qf[ec] = *(const bf16x8*)(Qrow + (size_t)(((ec * 4 + quad) ^ (nm & 7)) * 8));

    f32x4 O[8];
    #pragma unroll
    for (int i = 0; i < 8; i++) O[i] = (f32x4){0.f, 0.f, 0.f, 0.f};
    float m_cur[4], l_cur[4];
    #pragma unroll
    for (int r = 0; r < 4; r++) { m_cur[r] = -INFINITY; l_cur[r] = 0.0f; }

    // K staging: straight sequential copy of the 16KB tile (swizzle pre-baked)
    auto stage = [&](int tile, int buf) {
        const unsigned short* src0 = Kbase + (size_t)tile * 32 * E_DIM;
        #pragma unroll
        for (int k = 0; k < 4; k++) {
            int chunk = w * 4 + k;                 // 0..15, 1KB each
            __builtin_amdgcn_global_load_lds(
                (const __attribute__((address_space(1))) unsigned int*)
                    (src0 + (size_t)chunk * 512 + lane * 8),
                (__attribute__((address_space(3))) unsigned int*)
                    (&Kbuf[buf][chunk * 512]),
                16, 0, 0);
        }
    };

    stage(0, 0);
    int vswz = (quad ^ ((nm >> 1) & 3)) * 8;

    for (int it = 0; it < ITERS; ++it) {
        __syncthreads();                 // drains staging of tile `it`
        int cur = it & 1;

        // ---- V fragment prefetch (this iter), contiguous 1KB per instr ----
        const unsigned short* Vt = Vtile0 + (size_t)it * (H_DIM * 32);
        bf16x8 vf[8];
        #pragma unroll
        for (int tt = 0; tt < 8; tt++) {
            int hc = hbase + tt * 16 + nm;
            vf[tt] = *(const bf16x8*)(Vt + (size_t)(hc * 4) * 8 + vswz);
        }

        if (it + 1 < ITERS) stage(it + 1, cur ^ 1);
        const unsigned short* KB = &Kbuf[cur][0];

        // ---- QK^T: 16 q-rows x 32 keys, K=256 ----
        f32x4 s0 = (f32x4){0.f,0.f,0.f,0.f}, s1 = (f32x4){0.f,0.f,0.f,0.f};
        #pragma unroll
        for (int ec = 0; ec < 8; ec++) {
            int u = ((ec * 4 + quad) ^ (nm & 7)) * 8;
            bf16x8 kf0 = *(const bf16x8*)(KB + nm * 256 + u);
            bf16x8 kf1 = *(const bf16x8*)(KB + (16 + nm) * 256 + u);
            s0 = __builtin_amdgcn_mfma_f32_16x16x32_bf16(qf[ec], kf0, s0, 0, 0, 0);
            s1 = __builtin_amdgcn_mfma_f32_16x16x32_bf16(qf[ec], kf1, s1, 0, 0, 0);
        }

        // ---- wave-local online softmax (rows quad*4+r, reduce over 16 nm) --
        float alpha[4];
        #pragma unroll
        for (int r = 0; r < 4; r++) {
            float v = fmaxf(s0[r], s1[r]);
            #pragma unroll
            for (int o = 1; o < 16; o <<= 1) v = fmaxf(v, __shfl_xor(v, o));
            float mn = fmaxf(m_cur[r], v);
            alpha[r] = __expf(m_cur[r] - mn);
            m_cur[r] = mn;
            unsigned short pb0 = f2bf(__expf(s0[r] - mn));
            unsigned short pb1 = f2bf(__expf(s1[r] - mn));
            float ps = bf2f(pb0) + bf2f(pb1);
            #pragma unroll
            for (int o = 1; o < 16; o <<= 1) ps += __shfl_xor(ps, o);
            l_cur[r] = l_cur[r] * alpha[r] + ps;
            Pt[w][(quad * 4 + r) * PT_STRIDE + nm]      = pb0;
            Pt[w][(quad * 4 + r) * PT_STRIDE + 16 + nm] = pb1;
        }

        // ---- rescale O while the Pt writes land ----
        #pragma unroll
        for (int tt = 0; tt < 8; tt++)
            #pragma unroll
            for (int r = 0; r < 4; r++)
                O[tt][r] *= alpha[r];

        asm volatile("s_waitcnt lgkmcnt(0)" ::: "memory");
        __builtin_amdgcn_wave_barrier();
        bf16x8 pf = *(const bf16x8*)(&Pt[w][nm * PT_STRIDE + quad * 8]);

        // ---- PV (8 col-tiles x K=32) ----
        #pragma unroll
        for (int tt = 0; tt < 8; tt++)
            O[tt] = __builtin_amdgcn_mfma_f32_16x16x32_bf16(pf, vf[tt], O[tt], 0, 0, 0);
    }

    // ---- epilogue: divide by l, write unnormalized g, accumulate sumsq ----
    float linv[4];
    #pragma unroll
    for (int r = 0; r < 4; r++) linv[r] = 1.0f / l_cur[r];

    float ss = 0.0f;
    #pragma unroll
    for (int tt = 0; tt < 8; tt++) {
        #pragma unroll
        for (int r = 0; r < 4; r++) {
            float val = O[tt][r] * linv[r];
            int row = q0 + rg * 16 + quad * 4 + r;
            int col = hbase + tt * 16 + nm;
            out[((size_t)row * B_SZ + b) * H_DIM + col] = val;
            ss += val * val;
        }
    }
    #pragma unroll
    for (int o = 1; o < 64; o <<= 1) ss += __shfl_xor(ss, o);
    if (lane == 0) atomicAdd(sumsq, ss);
}

// ---- Kernel 4: global-norm rescale ----------------------------------------
__global__ void scale_kernel(float* __restrict__ out,
                             const float* __restrict__ sumsq) {
    size_t idx = ((size_t)blockIdx.x * blockDim.x + threadIdx.x) * 4;
    float rs = 1.0f / sqrtf(*sumsq);
    float4 v = *(float4*)(out + idx);
    v.x *= rs; v.y *= rs; v.z *= rs; v.w *= rs;
    *(float4*)(out + idx) = v;
}

extern "C" void kernel_launch(void* const* d_in, const int* in_sizes, int n_in,
                              void* d_out, int out_size, void* d_ws, size_t ws_size,
                              hipStream_t stream) {
    const float* x = (const float*)d_in[0];
    const float* h = (const float*)d_in[1];
    float* out = (float*)d_out;

    unsigned short* Xn = (unsigned short*)d_ws;                  // 8.4 MB
    unsigned short* Vp = Xn + (size_t)B_SZ * N_TOK * E_DIM;      // 16.8 MB
    float* sumsq = (float*)(Vp + (size_t)B_SZ * N_TOK * H_DIM); // 4 B

    hipMemsetAsync(sumsq, 0, sizeof(float), stream);
    norm_kernel<<<N_TOK * B_SZ, 256, 0, stream>>>(x, Xn);
    pack_v<<<dim3(N_TOK / 32, H_DIM / 32, B_SZ), 256, 0, stream>>>(h, Vp);
    flash_kernel<<<dim3(B_SZ, N_TOK / 32, 2), 256, 0, stream>>>(Xn, Vp, out, sumsq);
    scale_kernel<<<out_size / (4 * 256), 256, 0, stream>>>(out, sumsq);
}

// Round 7
// 226.831 us; speedup vs baseline: 2.2887x; 1.6222x over previous
//
#include <hip/hip_runtime.h>
#include <hip/hip_bf16.h>

#define N_TOK 2048
#define B_SZ  8
#define E_DIM 256
#define H_DIM 512
#define ITERS (N_TOK / 32)     // 64

typedef __attribute__((ext_vector_type(8))) short bf16x8;
typedef __attribute__((ext_vector_type(4))) float f32x4;

__device__ __forceinline__ unsigned short f2bf(float f) {
    union { float f; unsigned u; } v; v.f = f;
    unsigned r = v.u + 0x7FFF + ((v.u >> 16) & 1);   // RNE
    return (unsigned short)(r >> 16);
}
__device__ __forceinline__ float bf2f(unsigned short b) {
    union { unsigned u; float f; } v; v.u = ((unsigned)b) << 16;
    return v.f;
}

// ---- Kernel 1: fused prep ---------------------------------------------------
// blocks [0, 16384): row-normalize x -> Xn bf16 (B,N,E), 16B units XOR-swizzled
//   (unit u of row r stored at position u ^ (r & 7))
// blocks [16384, 24576): pack h (N,B,H) f32 -> Vp (B, N/32, H, 32) bf16,
//   swizzled: 16B unit (h, jg) stored at h*4 + (jg ^ ((h>>1)&3))
__global__ void prep_kernel(const float* __restrict__ x,
                            const float* __restrict__ hptr,
                            unsigned short* __restrict__ Xn,
                            unsigned short* __restrict__ Vp) {
    int bid = blockIdx.x;
    int t = threadIdx.x;
    if (bid < N_TOK * B_SZ) {
        // ---- norm path ----
        int r = bid;                   // r = i*B + b  (memory order of x)
        int i = r >> 3, b = r & 7;
        float v = x[(size_t)r * E_DIM + t];
        float s = v * v;
        #pragma unroll
        for (int o = 32; o > 0; o >>= 1) s += __shfl_xor(s, o);
        __shared__ float red[4];
        int lane = t & 63, w = t >> 6;
        if (lane == 0) red[w] = s;
        __syncthreads();
        float tot = red[0] + red[1] + red[2] + red[3];
        float rn = 1.0f / sqrtf(tot);
        int u = t >> 3, lo = t & 7;
        Xn[((size_t)b * N_TOK + i) * E_DIM + (size_t)((u ^ (i & 7)) * 8 + lo)] =
            f2bf(v * rn);
    } else {
        // ---- pack-V path ----
        int lin = bid - N_TOK * B_SZ;          // 8192 blocks: (64, 16, 8)
        int jb = lin & 63, hb = (lin >> 6) & 15, b = lin >> 10;
        __shared__ float tile[32][33];
        int j0 = jb * 32, h0 = hb * 32;
        int tx = t & 31, ty = t >> 5;          // 32 x 8
        #pragma unroll
        for (int it = 0; it < 4; it++) {
            int j = j0 + ty + it * 8;
            tile[ty + it * 8][tx] = hptr[((size_t)j * B_SZ + b) * H_DIM + h0 + tx];
        }
        __syncthreads();
        size_t base = ((size_t)b * (N_TOK / 32) + jb) * (H_DIM * 32);
        #pragma unroll
        for (int it = 0; it < 4; it++) {
            int hc = h0 + ty + it * 8;
            int jg = tx >> 3, swz = (hc >> 1) & 3;
            Vp[base + (size_t)(hc * 4 + (jg ^ swz)) * 8 + (tx & 7)] =
                f2bf(tile[tx][ty + it * 8]);
        }
    }
}

// ---- Kernel 2: fused flash attention, no-max softmax ----------------------
// Scores are cosine similarities in [-1,1] (diag == 1), so softmax is stable
// with FIXED shift m=1: P = exp(s-1), l accumulates per-lane — no max
// reduction, no alpha rescale, no cross-lane ops in the K-loop.
// grid (B=8, N/32=64): x=batch (XCD pin). 256 threads (4 waves).
// Wave w: rg=w>>1 (16 q-rows, QK dup x2), hh=w&1 (256 h-cols).
#define PT_STRIDE 40   // shorts

__launch_bounds__(256, 2)
__global__ void flash_kernel(const unsigned short* __restrict__ Xn,
                             const unsigned short* __restrict__ Vp,
                             float* __restrict__ out,
                             float* __restrict__ sumsq) {
    __shared__ __attribute__((aligned(16))) unsigned short Kbuf[2][32 * 256];
    __shared__ __attribute__((aligned(16))) unsigned short Pt[4][16 * PT_STRIDE];

    int b  = blockIdx.x;           // batch: linear-id % 8 == b -> XCD-pinned
    int q0 = blockIdx.y * 32;
    int t = threadIdx.x;
    int w = t >> 6, lane = t & 63;
    int quad = lane >> 4, nm = lane & 15;
    int rg = w >> 1, hh = w & 1;

    const unsigned short* Kbase = Xn + (size_t)b * N_TOK * E_DIM;
    const unsigned short* Qrow =
        Xn + ((size_t)b * N_TOK + q0 + rg * 16 + nm) * E_DIM;
    const unsigned short* Vtile0 = Vp + (size_t)b * (N_TOK / 32) * (H_DIM * 32);

    // Q fragments (swizzled layout: unit (ec*4+quad) ^ (row&7))
    bf16x8 qf[8];
    #pragma unroll
    for (int ec = 0; ec < 8; ec++)
        qf[ec] = *(const bf16x8*)(Qrow + (size_t)(((ec * 4 + quad) ^ (nm & 7)) * 8));

    f32x4 O[16];
    #pragma unroll
    for (int i = 0; i < 16; i++) O[i] = (f32x4){0.f, 0.f, 0.f, 0.f};
    float l_lane[4];
    #pragma unroll
    for (int r = 0; r < 4; r++) l_lane[r] = 0.0f;

    // K staging: straight sequential copy of the 16KB tile (swizzle pre-baked)
    auto stage = [&](int tile, int buf) {
        const unsigned short* src0 = Kbase + (size_t)tile * 32 * E_DIM;
        #pragma unroll
        for (int k = 0; k < 4; k++) {
            int chunk = w * 4 + k;                 // 0..15, 1KB each
            __builtin_amdgcn_global_load_lds(
                (const __attribute__((address_space(1))) unsigned int*)
                    (src0 + (size_t)chunk * 512 + lane * 8),
                (__attribute__((address_space(3))) unsigned int*)
                    (&Kbuf[buf][chunk * 512]),
                16, 0, 0);
        }
    };

    stage(0, 0);
    int vswz = (quad ^ ((nm >> 1) & 3)) * 8;

    for (int it = 0; it < ITERS; ++it) {
        __syncthreads();                 // drains staging of tile `it`
        int cur = it & 1;

        // ---- V fragment prefetch (this iter), contiguous 1KB per instr ----
        const unsigned short* Vt = Vtile0 + (size_t)it * (H_DIM * 32);
        bf16x8 vf[16];
        #pragma unroll
        for (int tt = 0; tt < 16; tt++) {
            int hc = hh * 256 + tt * 16 + nm;
            vf[tt] = *(const bf16x8*)(Vt + (size_t)(hc * 4) * 8 + vswz);
        }

        if (it + 1 < ITERS) stage(it + 1, cur ^ 1);
        const unsigned short* KB = &Kbuf[cur][0];

        // ---- QK^T: 16 q-rows x 32 keys, K=256 ----
        f32x4 s0 = (f32x4){0.f,0.f,0.f,0.f}, s1 = (f32x4){0.f,0.f,0.f,0.f};
        #pragma unroll
        for (int ec = 0; ec < 8; ec++) {
            int u = ((ec * 4 + quad) ^ (nm & 7)) * 8;
            bf16x8 kf0 = *(const bf16x8*)(KB + nm * 256 + u);
            bf16x8 kf1 = *(const bf16x8*)(KB + (16 + nm) * 256 + u);
            s0 = __builtin_amdgcn_mfma_f32_16x16x32_bf16(qf[ec], kf0, s0, 0, 0, 0);
            s1 = __builtin_amdgcn_mfma_f32_16x16x32_bf16(qf[ec], kf1, s1, 0, 0, 0);
        }

        // ---- fixed-shift softmax: P = exp(s-1), purely elementwise ----
        #pragma unroll
        for (int r = 0; r < 4; r++) {
            unsigned short pb0 = f2bf(__expf(s0[r] - 1.0f));
            unsigned short pb1 = f2bf(__expf(s1[r] - 1.0f));
            l_lane[r] += bf2f(pb0) + bf2f(pb1);
            Pt[w][(quad * 4 + r) * PT_STRIDE + nm]      = pb0;
            Pt[w][(quad * 4 + r) * PT_STRIDE + 16 + nm] = pb1;
        }

        asm volatile("s_waitcnt lgkmcnt(0)" ::: "memory");
        __builtin_amdgcn_wave_barrier();
        bf16x8 pf = *(const bf16x8*)(&Pt[w][nm * PT_STRIDE + quad * 8]);

        // ---- PV (16 col-tiles x K=32), no rescale needed ----
        #pragma unroll
        for (int tt = 0; tt < 16; tt++)
            O[tt] = __builtin_amdgcn_mfma_f32_16x16x32_bf16(pf, vf[tt], O[tt], 0, 0, 0);
    }

    // ---- epilogue: reduce l over the 16 key-lanes, scale, write, sumsq ----
    float linv[4];
    #pragma unroll
    for (int r = 0; r < 4; r++) {
        float lv = l_lane[r];
        #pragma unroll
        for (int o = 1; o < 16; o <<= 1) lv += __shfl_xor(lv, o);
        linv[r] = 1.0f / lv;
    }

    float ss = 0.0f;
    #pragma unroll
    for (int tt = 0; tt < 16; tt++) {
        #pragma unroll
        for (int r = 0; r < 4; r++) {
            float val = O[tt][r] * linv[r];
            int row = q0 + rg * 16 + quad * 4 + r;
            int col = hh * 256 + tt * 16 + nm;
            out[((size_t)row * B_SZ + b) * H_DIM + col] = val;
            ss += val * val;
        }
    }
    #pragma unroll
    for (int o = 1; o < 64; o <<= 1) ss += __shfl_xor(ss, o);
    if (lane == 0) atomicAdd(sumsq, ss);
}

// ---- Kernel 3: global-norm rescale ----------------------------------------
__global__ void scale_kernel(float* __restrict__ out,
                             const float* __restrict__ sumsq) {
    size_t idx = ((size_t)blockIdx.x * blockDim.x + threadIdx.x) * 4;
    float rs = 1.0f / sqrtf(*sumsq);
    float4 v = *(float4*)(out + idx);
    v.x *= rs; v.y *= rs; v.z *= rs; v.w *= rs;
    *(float4*)(out + idx) = v;
}

extern "C" void kernel_launch(void* const* d_in, const int* in_sizes, int n_in,
                              void* d_out, int out_size, void* d_ws, size_t ws_size,
                              hipStream_t stream) {
    const float* x = (const float*)d_in[0];
    const float* h = (const float*)d_in[1];
    float* out = (float*)d_out;

    unsigned short* Xn = (unsigned short*)d_ws;                  // 8.4 MB
    unsigned short* Vp = Xn + (size_t)B_SZ * N_TOK * E_DIM;      // 16.8 MB
    float* sumsq = (float*)(Vp + (size_t)B_SZ * N_TOK * H_DIM); // 4 B

    hipMemsetAsync(sumsq, 0, sizeof(float), stream);
    prep_kernel<<<N_TOK * B_SZ + (N_TOK / 32) * (H_DIM / 32) * B_SZ,
                  256, 0, stream>>>(x, h, Xn, Vp);
    flash_kernel<<<dim3(B_SZ, N_TOK / 32), 256, 0, stream>>>(Xn, Vp, out, sumsq);
    scale_kernel<<<out_size / (4 * 256), 256, 0, stream>>>(out, sumsq);
}